// Round 1
// baseline (801.139 us; speedup 1.0000x reference)
//
#include <hip/hip_runtime.h>
#include <math.h>

#define NB   4
#define IH   128
#define IW   128
#define NTOK 16384        // IH*IW
#define CC   96
#define HID  192
#define QKD  48
#define EPSF 1e-5f
#define INV_N (1.0f/16384.0f)

__device__ __forceinline__ float wave_sum64(float v){
    #pragma unroll
    for (int off = 32; off > 0; off >>= 1) v += __shfl_xor(v, off, 64);
    return v;
}
__device__ __forceinline__ float siluf(float x){ return x / (1.0f + expf(-x)); }
__device__ __forceinline__ float geluf(float x){ return 0.5f*x*(1.0f + erff(x*0.7071067811865475f)); }

// ---------------- 1. LayerNorm over C=96, wave per row ----------------
__global__ __launch_bounds__(256) void k_ln(const float* __restrict__ x,
                                            const float* __restrict__ w,
                                            const float* __restrict__ bb,
                                            float* __restrict__ nx){
    int row = blockIdx.x*4 + (threadIdx.x >> 6);
    int l = threadIdx.x & 63;
    const float* xr = x + (size_t)row*CC;
    float a = xr[l];
    float b = (l < 32) ? xr[64+l] : 0.0f;
    float s = wave_sum64(a + b);
    float m = s * (1.0f/96.0f);
    float d1 = a - m;
    float d2 = b - m;
    float sq = d1*d1 + ((l < 32) ? d2*d2 : 0.0f);
    float var = wave_sum64(sq) * (1.0f/96.0f);
    float rstd = rsqrtf(var + EPSF);
    float* o = nx + (size_t)row*CC;
    o[l] = d1*rstd*w[l] + bb[l];
    if (l < 32) o[64+l] = d2*rstd*w[64+l] + bb[64+l];
}

// ---------------- 2. h = silu(nx @ Wh + bh); split v/gate ----------------
// 32 rows x 192 cols per block, 256 threads, K-chunks of 32 with transposed padded W tile.
__global__ __launch_bounds__(256) void k_hgemm(const float* __restrict__ nx,
                                               const float* __restrict__ Wh,
                                               const float* __restrict__ bh,
                                               float* __restrict__ vbuf,
                                               float* __restrict__ gate){
    __shared__ float xs[32*96];
    __shared__ float wt[192*36];   // wt[col][k] padded stride 36
    int tid = threadIdx.x;
    int row0 = blockIdx.x * 32;
    for (int i = tid; i < 32*96; i += 256)
        xs[i] = nx[(size_t)(row0 + i/96)*CC + (i%96)];
    int tc = tid & 31, tr = tid >> 5;
    float acc[4][6];
    #pragma unroll
    for (int i = 0; i < 4; i++)
        #pragma unroll
        for (int j = 0; j < 6; j++) acc[i][j] = 0.0f;

    for (int k0 = 0; k0 < 96; k0 += 32){
        __syncthreads();
        for (int idx = tid; idx < 32*192; idx += 256){
            int kk = idx / 192, col = idx % 192;
            wt[col*36 + kk] = Wh[(size_t)(k0+kk)*HID + col];
        }
        __syncthreads();
        #pragma unroll
        for (int k4 = 0; k4 < 8; k4++){
            float4 xa[4], wb[6];
            #pragma unroll
            for (int i = 0; i < 4; i++)
                xa[i] = *(const float4*)&xs[(tr*4+i)*96 + k0 + k4*4];
            #pragma unroll
            for (int j = 0; j < 6; j++)
                wb[j] = *(const float4*)&wt[(tc + j*32)*36 + k4*4];
            #pragma unroll
            for (int i = 0; i < 4; i++)
                #pragma unroll
                for (int j = 0; j < 6; j++){
                    acc[i][j] += xa[i].x*wb[j].x + xa[i].y*wb[j].y
                               + xa[i].z*wb[j].z + xa[i].w*wb[j].w;
                }
        }
    }
    #pragma unroll
    for (int i = 0; i < 4; i++){
        size_t row = row0 + tr*4 + i;
        #pragma unroll
        for (int j = 0; j < 6; j++){
            int col = tc + j*32;
            float hv = siluf(acc[i][j] + bh[col]);
            if (col < 96) vbuf[row*CC + col] = hv;
            else          gate[row*CC + col - 96] = hv;
        }
    }
}

// ---------------- 3. conv (patch GEMM, K-split) ----------------
// grid = rowblocks * nsplit ; 64 positions x 96 out-channels per block; K chunk 96, 2 chunks per block (192 K per split)
__global__ __launch_bounds__(256) void k_conv(const float* __restrict__ nx,
                                              const float* __restrict__ wconv,
                                              float* __restrict__ part,
                                              int posLog,   // 8 (256 pos) or 10 (1024)
                                              int pdimLog,  // 4 or 5
                                              int pszLog,   // 3 or 2
                                              int kTotal){  // 6144 or 1536
    __shared__ float pt[64*96];    // pt[r][kk]
    __shared__ float wt[96*100];   // wt[o][kk] padded
    int posPerImg = 1 << posLog;
    int pdim = 1 << pdimLog;
    int psz  = 1 << pszLog;
    int ksLog = 2*pszLog;
    int rowblocks = (NB << posLog) >> 6;
    int rb = blockIdx.x % rowblocks;
    int split = blockIdx.x / rowblocks;
    int tid = threadIdx.x;
    int to = tid & 15, ty = tid >> 4;
    float acc[4][6];
    #pragma unroll
    for (int i = 0; i < 4; i++)
        #pragma unroll
        for (int j = 0; j < 6; j++) acc[i][j] = 0.0f;

    for (int half = 0; half < 2; half++){
        int kb = split*192 + half*96;
        __syncthreads();
        for (int idx = tid; idx < 96*96; idx += 256){
            int o = idx / 96, kk = idx % 96;
            wt[o*100 + kk] = wconv[(size_t)o*kTotal + kb + kk];
        }
        for (int idx = tid; idx < 64*96; idx += 256){
            int r = idx / 96, kk = idx % 96;
            int R = rb*64 + r;
            int b = R >> posLog, p = R & (posPerImg-1);
            int k = kb + kk;
            int c = k >> ksLog, s = k & ((psz*psz)-1);
            int pi = p >> pdimLog, pj = p & (pdim-1);
            int px = (pi << pszLog) + (s >> pszLog);
            int py = (pj << pszLog) + (s & (psz-1));
            pt[r*96 + kk] = nx[((size_t)b*NTOK + px*IW + py)*CC + c];
        }
        __syncthreads();
        #pragma unroll 4
        for (int k4 = 0; k4 < 24; k4++){
            float4 xa[4], wb[6];
            #pragma unroll
            for (int i = 0; i < 4; i++)
                xa[i] = *(const float4*)&pt[(ty*4+i)*96 + k4*4];
            #pragma unroll
            for (int j = 0; j < 6; j++)
                wb[j] = *(const float4*)&wt[(to + j*16)*100 + k4*4];
            #pragma unroll
            for (int i = 0; i < 4; i++)
                #pragma unroll
                for (int j = 0; j < 6; j++){
                    acc[i][j] += xa[i].x*wb[j].x + xa[i].y*wb[j].y
                               + xa[i].z*wb[j].z + xa[i].w*wb[j].w;
                }
        }
    }
    int rowsTotal = NB << posLog;
    #pragma unroll
    for (int i = 0; i < 4; i++){
        int R = rb*64 + ty*4 + i;
        #pragma unroll
        for (int j = 0; j < 6; j++){
            int o = to + j*16;
            part[((size_t)split*rowsTotal + R)*96 + o] = acc[i][j];
        }
    }
}

// ---------------- 4. reduce K-splits + bias + LN + gelu + Z/q/k ----------------
__global__ __launch_bounds__(64) void k_reduce(const float* __restrict__ part,
                                               int nsplit, int rows,
                                               const float* __restrict__ cbias,
                                               const float* __restrict__ lw,
                                               const float* __restrict__ lb,
                                               const float* __restrict__ wqk,
                                               const float* __restrict__ bqk,
                                               const float* __restrict__ g,
                                               const float* __restrict__ be,
                                               float* __restrict__ qout,
                                               float* __restrict__ kout){
    __shared__ float xsh[96];
    int row = blockIdx.x;
    int l = threadIdx.x;
    float y1 = 0.0f, y2 = 0.0f;
    for (int s = 0; s < nsplit; s++){
        const float* pr = part + ((size_t)s*rows + row)*96;
        y1 += pr[l];
        if (l < 32) y2 += pr[64+l];
    }
    y1 += cbias[l];
    if (l < 32) y2 += cbias[64+l];
    float s = wave_sum64(y1 + ((l < 32) ? y2 : 0.0f));
    float m = s * (1.0f/96.0f);
    float d1 = y1 - m, d2 = y2 - m;
    float var = wave_sum64(d1*d1 + ((l < 32) ? d2*d2 : 0.0f)) * (1.0f/96.0f);
    float rstd = rsqrtf(var + EPSF);
    xsh[l] = geluf(d1*rstd*lw[l] + lb[l]);
    if (l < 32) xsh[64+l] = geluf(d2*rstd*lw[64+l] + lb[64+l]);
    __syncthreads();
    if (l < 48){
        float z = bqk[l];
        #pragma unroll 4
        for (int c = 0; c < 96; c++) z += xsh[c]*wqk[c*48 + l];
        z = siluf(z);
        qout[(size_t)row*48 + l] = z*g[l]    + be[l];
        kout[(size_t)row*48 + l] = z*g[48+l] + be[48+l];
    }
}

// ---------------- 5. attention: thread-per-row, LDS m-chunks of 64 ----------------
// kind 0: branch1 (m 0..255) -> V1 ; kind 1: branch2 m 0..511 -> V2a ; kind 2: branch2 m 512..1023 -> V2b
__global__ __launch_bounds__(256) void k_attn(const float* __restrict__ vbuf,
                                              const float* __restrict__ q1,
                                              const float* __restrict__ k1,
                                              const float* __restrict__ q2,
                                              const float* __restrict__ k2,
                                              float* __restrict__ V1,
                                              float* __restrict__ V2a,
                                              float* __restrict__ V2b){
    __shared__ float4 qs[64*12];
    __shared__ float4 ks[64*12];
    int bx = blockIdx.x;
    int kind = bx >> 8;
    int rem = bx & 255;
    int b = rem >> 6;
    int rb = rem & 63;
    int row = b*NTOK + rb*256 + threadIdx.x;

    const float* qsrc; const float* ksrc; float* outb;
    int mbase0, nchunk, voff;
    if (kind == 0){
        qsrc = q1 + (size_t)b*256*48; ksrc = k1 + (size_t)b*256*48;
        outb = V1; mbase0 = 0; nchunk = 4; voff = 0;
    } else if (kind == 1){
        qsrc = q2 + (size_t)b*1024*48; ksrc = k2 + (size_t)b*1024*48;
        outb = V2a; mbase0 = 0; nchunk = 8; voff = 48;
    } else {
        qsrc = q2 + (size_t)b*1024*48; ksrc = k2 + (size_t)b*1024*48;
        outb = V2b; mbase0 = 512; nchunk = 8; voff = 48;
    }
    float4 vv[12], acc[12];
    const float4* vg = (const float4*)(vbuf + (size_t)row*CC + voff);
    #pragma unroll
    for (int i = 0; i < 12; i++){ vv[i] = vg[i]; acc[i] = make_float4(0.f,0.f,0.f,0.f); }

    const float4* qg = (const float4*)qsrc;
    const float4* kg = (const float4*)ksrc;
    for (int ch = 0; ch < nchunk; ch++){
        int mb = mbase0 + ch*64;
        __syncthreads();
        for (int i = threadIdx.x; i < 768; i += 256){
            qs[i] = qg[(size_t)mb*12 + i];
            ks[i] = kg[(size_t)mb*12 + i];
        }
        __syncthreads();
        #pragma unroll 2
        for (int mm = 0; mm < 64; mm++){
            const float4* qrow = &qs[mm*12];
            float s0=0.f, s1=0.f, s2=0.f, s3=0.f;
            #pragma unroll
            for (int i = 0; i < 12; i++){
                float4 q = qrow[i]; float4 a = vv[i];
                s0 += a.x*q.x; s1 += a.y*q.y; s2 += a.z*q.z; s3 += a.w*q.w;
            }
            float p = ((s0+s1)+(s2+s3))*INV_N;
            p = (p > 0.f) ? p*p : 0.f;
            const float4* krow = &ks[mm*12];
            #pragma unroll
            for (int i = 0; i < 12; i++){
                float4 kv = krow[i];
                acc[i].x += p*kv.x; acc[i].y += p*kv.y;
                acc[i].z += p*kv.z; acc[i].w += p*kv.w;
            }
        }
    }
    float4* o = (float4*)(outb + (size_t)row*48);
    #pragma unroll
    for (int i = 0; i < 12; i++) o[i] = acc[i];
}

// ---------------- 6. final: xc, gate, proj, residual ----------------
__global__ __launch_bounds__(256) void k_final(const float* __restrict__ V1,
                                               const float* __restrict__ V2a,
                                               const float* __restrict__ V2b,
                                               const float* __restrict__ gate,
                                               const float* __restrict__ projw,
                                               const float* __restrict__ projb,
                                               float* __restrict__ out){
    __shared__ float pj[96*96];
    __shared__ float vsh[4][96];
    int tid = threadIdx.x;
    for (int i = tid; i < 96*96; i += 256) pj[i] = projw[i];
    int w = tid >> 6, l = tid & 63;
    size_t row = (size_t)blockIdx.x*4 + w;

    float xc1 = (l < 48) ? V1[row*48 + l]
                         : (V2a[row*48 + (l-48)] + V2b[row*48 + (l-48)]);
    float xc2 = 0.0f;
    if (l < 32) xc2 = V2a[row*48 + 16 + l] + V2b[row*48 + 16 + l];
    float ga = gate[row*CC + l];
    float gb = (l < 32) ? gate[row*CC + 64 + l] : 0.0f;
    vsh[w][l] = xc1*ga;
    if (l < 32) vsh[w][64+l] = xc2*gb;
    __syncthreads();

    float a0 = projb[l];
    float a1 = (l < 32) ? projb[64+l] : 0.0f;
    #pragma unroll 4
    for (int c = 0; c < 96; c++){
        float vv = vsh[w][c];
        a0 += vv*pj[c*96 + l];
        if (l < 32) a1 += vv*pj[c*96 + 64 + l];
    }
    out[row*CC + l] = a0 + xc1;
    if (l < 32) out[row*CC + 64 + l] = a1 + xc2;
}

extern "C" void kernel_launch(void* const* d_in, const int* in_sizes, int n_in,
                              void* d_out, int out_size, void* d_ws, size_t ws_size,
                              hipStream_t stream){
    const float* x      = (const float*)d_in[0];
    const float* norm_w = (const float*)d_in[3];
    const float* norm_b = (const float*)d_in[4];
    const float* Wh     = (const float*)d_in[5];
    const float* bh     = (const float*)d_in[6];
    const float* Wqk    = (const float*)d_in[7];
    const float* bqk    = (const float*)d_in[8];
    const float* g1     = (const float*)d_in[9];
    const float* be1    = (const float*)d_in[10];
    const float* g2     = (const float*)d_in[11];
    const float* be2    = (const float*)d_in[12];
    const float* sr1_w  = (const float*)d_in[13];
    const float* sr1_b  = (const float*)d_in[14];
    const float* sr2_w  = (const float*)d_in[15];
    const float* sr2_b  = (const float*)d_in[16];
    const float* n1_w   = (const float*)d_in[17];
    const float* n1_b   = (const float*)d_in[18];
    const float* n2_w   = (const float*)d_in[19];
    const float* n2_b   = (const float*)d_in[20];
    const float* proj_w = (const float*)d_in[21];
    const float* proj_b = (const float*)d_in[22];
    float* out = (float*)d_out;

    float* ws = (float*)d_ws;
    size_t off = 0;
    float* nx   = ws + off; off += (size_t)NB*NTOK*CC;   // 6.29M
    float* vbuf = ws + off; off += (size_t)NB*NTOK*CC;
    float* gate = ws + off; off += (size_t)NB*NTOK*CC;
    float* q1   = ws + off; off += (size_t)NB*256*48;
    float* k1   = ws + off; off += (size_t)NB*256*48;
    float* q2   = ws + off; off += (size_t)NB*1024*48;
    float* k2   = ws + off; off += (size_t)NB*1024*48;
    float* part1= ws + off; off += (size_t)32*NB*256*96;
    float* part2= ws + off; off += (size_t)8*NB*1024*96;
    float* V1   = ws + off; off += (size_t)NB*NTOK*48;
    float* V2a  = ws + off; off += (size_t)NB*NTOK*48;
    float* V2b  = ws + off; off += (size_t)NB*NTOK*48;
    if (ws_size < off*sizeof(float)) return;   // workspace too small: fail loudly (validation mismatch)

    k_ln   <<<16384, 256, 0, stream>>>(x, norm_w, norm_b, nx);
    k_hgemm<<<2048, 256, 0, stream>>>(nx, Wh, bh, vbuf, gate);
    k_conv <<<512, 256, 0, stream>>>(nx, sr1_w, part1, 8, 4, 3, 6144);
    k_conv <<<512, 256, 0, stream>>>(nx, sr2_w, part2, 10, 5, 2, 1536);
    k_reduce<<<1024, 64, 0, stream>>>(part1, 32, 1024, sr1_b, n1_w, n1_b, Wqk, bqk, g1, be1, q1, k1);
    k_reduce<<<4096, 64, 0, stream>>>(part2, 8, 4096, sr2_b, n2_w, n2_b, Wqk, bqk, g2, be2, q2, k2);
    k_attn <<<768, 256, 0, stream>>>(vbuf, q1, k1, q2, k2, V1, V2a, V2b);
    k_final<<<16384, 256, 0, stream>>>(V1, V2a, V2b, gate, proj_w, proj_b, out);
}